// Round 7
// baseline (45.784 us; speedup 1.0000x reference)
//
#include <hip/hip_runtime.h>
#include <hip/hip_bf16.h>

#define HW        1659      // 21*79
#define GLYPH_DIM 1536

typedef _Float16 half8  __attribute__((ext_vector_type(8)));
typedef _Float16 half2v __attribute__((ext_vector_type(2)));
typedef float    f32x4  __attribute__((ext_vector_type(4)));

__device__ __forceinline__ float tanh_f(float x) {
    // tanh(x) = 1 - 2/(e^{2x}+1); exp handles +-inf limits correctly
    float e = __expf(x + x);
    return fmaf(-2.0f, __builtin_amdgcn_rcpf(e + 1.0f), 1.0f);
}

__device__ __forceinline__ unsigned int pk(float a, float b) {
    return __builtin_bit_cast(unsigned int, __builtin_amdgcn_cvt_pkrtz(a, b));
}

__device__ __forceinline__ half8 h8(unsigned int a, unsigned int b,
                                    unsigned int c, unsigned int d) {
    uint4 u = make_uint4(a, b, c, d);
    return __builtin_bit_cast(half8, u);
}

// ---------------- K1: histogram -> sorted unique ids + lens -> workspace ----
// 4 batches/block, tiny LDS, high occupancy, 2-deep global-load pipeline.
__global__ __launch_bounds__(256, 8) void k1_histo(
    const int* __restrict__ gchar, const int* __restrict__ gcol,
    unsigned short* __restrict__ ids_bt,   // [B][64]
    unsigned short* __restrict__ ids_tb,   // [B/64][64 t][64 b-in-group]
    int* __restrict__ lens_g)
{
    __shared__ unsigned int   mask[4][48];
    __shared__ unsigned short ids_s[4][64];

    const int tid = threadIdx.x;
    const int b0  = blockIdx.x * 4;

    if (tid < 192) ((unsigned int*)mask)[tid] = 0u;
    __syncthreads();

    // phase A: bitmap histogram, 2-deep software pipeline
    const int4* cp = (const int4*)(gchar + (long)b0 * HW);
    const int4* kp = (const int4*)(gcol  + (long)b0 * HW);
    const int n4 = HW;   // 4*HW ints / 4 per int4 = 1659
    int idx = tid;
    bool valid = idx < n4;
    int4 c = {}, k = {};
    if (valid) { c = cp[idx]; k = kp[idx]; }
    while (valid) {
        int  idx1 = idx + 256;
        bool v1   = idx1 < n4;
        int4 c1 = {}, k1 = {};
        if (v1) { c1 = cp[idx1]; k1 = kp[idx1]; }
        {
            int gg  = idx * 4;
            int bl0 = gg / HW;               // const-div -> magic mul
            int rem = gg - bl0 * HW;
            int bl1 = bl0 + ((rem + 1) >= HW);
            int bl2 = bl0 + ((rem + 2) >= HW);
            int bl3 = bl0 + ((rem + 3) >= HW);
            int id0 = c.x * 16 + k.x;
            int id1 = c.y * 16 + k.y;
            int id2 = c.z * 16 + k.z;
            int id3 = c.w * 16 + k.w;
            atomicOr(&mask[bl0][id0 >> 5], 1u << (id0 & 31));
            atomicOr(&mask[bl1][id1 >> 5], 1u << (id1 & 31));
            atomicOr(&mask[bl2][id2 >> 5], 1u << (id2 & 31));
            atomicOr(&mask[bl3][id3 >> 5], 1u << (id3 & 31));
        }
        idx = idx1; valid = v1; c = c1; k = k1;
    }
    __syncthreads();

    // phase B: first-64 sorted set bits per batch (threads 0-127)
    if (tid < 128) {
        const int bl  = tid >> 5;
        const int l32 = tid & 31;
        unsigned long long m = 0ull;
        if (l32 < 24)
            m = ((unsigned long long)mask[bl][2 * l32 + 1] << 32) |
                (unsigned long long)mask[bl][2 * l32];
        int cnt  = __popcll(m);
        int incl = cnt;
        #pragma unroll
        for (int d = 1; d < 32; d <<= 1) {
            int nb = __shfl_up(incl, d, 32);
            if (l32 >= d) incl += nb;
        }
        int excl  = incl - cnt;
        int total = __shfl(incl, 31, 32);
        if (l32 == 0) lens_g[b0 + bl] = min(total, 64);
        ids_s[bl][l32]      = GLYPH_DIM;   // sentinel prefill (same-wave order)
        ids_s[bl][l32 + 32] = GLYPH_DIM;
        unsigned long long mm = m;
        int r = excl;
        while (mm != 0ull && r < 64) {
            int bit = __builtin_ctzll(mm);
            ids_s[bl][r] = (unsigned short)(l32 * 64 + bit);
            ++r;
            mm &= (mm - 1ull);
        }
    }
    __syncthreads();

    // write layout A: ids_bt[b][t], coalesced u32 (threads 0-127)
    if (tid < 128)
        ((unsigned int*)(ids_bt + (long)b0 * 64))[tid] = ((unsigned int*)ids_s)[tid];
    // write layout B: ids_tb[b>>6][t][b&63], scattered u16 (all 256)
    {
        const int bl = tid >> 6, t = tid & 63;
        const int b  = b0 + bl;
        ids_tb[((long)(b >> 6) * 64 + t) * 64 + (b & 63)] = ids_s[bl][t];
    }
}

// ---------------- K23: blocks [0,nrnn): MFMA RNN; blocks [nrnn,..): emb/bag.
// Fragment k-map tau(g,j) = {4g..4g+3, 16+4g..19+4g} used consistently for A
// and B so the HW k-permutation cancels; with this tau the C/D layout
// (col=lane&15, row=(lane>>4)*4+reg) IS the next step's B-fragment layout.
__global__ __launch_bounds__(256, 4) void k23_main(
    const float* __restrict__ ctab, const float* __restrict__ ktab,
    const float* __restrict__ Wih, const float* __restrict__ Whh,
    const float* __restrict__ bih, const float* __restrict__ bhh,
    const unsigned short* __restrict__ ids_bt,
    const unsigned short* __restrict__ ids_tb,
    const int* __restrict__ lens_g,
    float* __restrict__ out_h, float* __restrict__ out_emb,
    float* __restrict__ out_bag, int nrnn)
{
    __shared__ float          tabs[1620];      // ctab 97*16 | ktab 17*4
    __shared__ unsigned short ids_t[64 * 64];  // [t][b-in-block]

    const int tid = threadIdx.x;

    // stage tables into LDS (both paths use them)
    for (int i = tid; i < 1620; i += 256)
        tabs[i] = (i < 1552) ? ctab[i] : ktab[i - 1552];

    if ((int)blockIdx.x < nrnn) {
        // ---------------- RNN path: 4 waves x 16 batches ----------------
        {   // stage this block's ids (transposed layout, linear copy)
            const unsigned int* src = (const unsigned int*)(ids_tb + (long)blockIdx.x * 4096);
            unsigned int* dst = (unsigned int*)ids_t;
            #pragma unroll
            for (int j = 0; j < 8; ++j) dst[tid + j * 256] = src[tid + j * 256];
        }
        const int n = tid & 15, g = (tid >> 4) & 3;
        half8 wihA0, wihA1, whhA0, whhA1;
        #pragma unroll
        for (int j = 0; j < 8; ++j) {
            int kk = (j < 4) ? (4 * g + j) : (12 + 4 * g + j);   // tau(g,j)
            wihA0[j] = (_Float16)((kk < 20) ? Wih[n * 20 + kk] : 0.0f);
            wihA1[j] = (_Float16)((kk < 20) ? Wih[(n + 16) * 20 + kk] : 0.0f);
            whhA0[j] = (_Float16)Whh[n * 32 + kk];
            whhA1[j] = (_Float16)Whh[(n + 16) * 32 + kk];
        }
        f32x4 bias0, bias1;
        #pragma unroll
        for (int i = 0; i < 4; ++i) {
            bias0[i] = bih[4 * g + i] + bhh[4 * g + i];
            bias1[i] = bih[16 + 4 * g + i] + bhh[16 + 4 * g + i];
        }
        const int ib  = (tid >> 6) * 16 + n;       // batch within block
        const int b   = blockIdx.x * 64 + ib;
        const int len = lens_g[b];
        __syncthreads();

        // x-fragment builder from an id (LDS gathers, off the serial chain)
        auto build = [&](int id) -> half8 {
            int ch = id >> 4;
            int co = (id >= GLYPH_DIM) ? 16 : (id & 15);
            f32x4 q1 = *(const f32x4*)&tabs[ch * 16 + 4 * g];
            f32x4 q2 = {0.0f, 0.0f, 0.0f, 0.0f};
            if (g == 0) q2 = *(const f32x4*)&tabs[1552 + co * 4];
            return h8(pk(q1[0], q1[1]), pk(q1[2], q1[3]),
                      pk(q2[0], q2[1]), pk(q2[2], q2[3]));
        };

        // pipeline: id 2 ahead, gather+Wih-MFMA 1 ahead
        half8 x0  = build(ids_t[0 * 64 + ib]);
        f32x4 Pc0 = __builtin_amdgcn_mfma_f32_16x16x32_f16(wihA0, x0, bias0, 0, 0, 0);
        f32x4 Pc1 = __builtin_amdgcn_mfma_f32_16x16x32_f16(wihA1, x0, bias1, 0, 0, 0);
        int   idn = ids_t[1 * 64 + ib];
        f32x4 d0 = {0, 0, 0, 0}, d1 = {0, 0, 0, 0};
        for (int t = 0; t < 64; ++t) {
            f32x4 Pn0 = Pc0, Pn1 = Pc1;
            int   id2 = (t < 62) ? (int)ids_t[(t + 2) * 64 + ib] : idn;
            if (t < 63) {
                half8 xn = build(idn);
                Pn0 = __builtin_amdgcn_mfma_f32_16x16x32_f16(wihA0, xn, bias0, 0, 0, 0);
                Pn1 = __builtin_amdgcn_mfma_f32_16x16x32_f16(wihA1, xn, bias1, 0, 0, 0);
            }
            half8 hB = h8(pk(d0[0], d0[1]), pk(d0[2], d0[3]),
                          pk(d1[0], d1[1]), pk(d1[2], d1[3]));
            f32x4 a0 = __builtin_amdgcn_mfma_f32_16x16x32_f16(whhA0, hB, Pc0, 0, 0, 0);
            f32x4 a1 = __builtin_amdgcn_mfma_f32_16x16x32_f16(whhA1, hB, Pc1, 0, 0, 0);
            bool upd = (t < len);
            #pragma unroll
            for (int i = 0; i < 4; ++i) {
                float h0 = tanh_f(a0[i]);
                float h1 = tanh_f(a1[i]);
                d0[i] = upd ? h0 : d0[i];
                d1[i] = upd ? h1 : d1[i];
            }
            Pc0 = Pn0; Pc1 = Pn1; idn = id2;
        }
        float* op = out_h + (long)b * 32;
        *(f32x4*)(op + 4 * g)      = d0;
        *(f32x4*)(op + 16 + 4 * g) = d1;
    } else {
        // ---------------- emb/bag path: 1 row per thread ----------------
        __syncthreads();
        const long row = (long)((int)blockIdx.x - nrnn) * 256 + tid;
        int id = ids_bt[row];
        int ch = id >> 4;                              // pad -> 96
        int co = (id >= GLYPH_DIM) ? 16 : (id & 15);   // pad -> 16
        f32x4 c0 = *(const f32x4*)&tabs[ch * 16 + 0];
        f32x4 c1 = *(const f32x4*)&tabs[ch * 16 + 4];
        f32x4 c2 = *(const f32x4*)&tabs[ch * 16 + 8];
        f32x4 c3 = *(const f32x4*)&tabs[ch * 16 + 12];
        f32x4 k0 = *(const f32x4*)&tabs[1552 + co * 4];
        float* gp = out_emb + row * 20;
        *(f32x4*)(gp + 0)  = c0;
        *(f32x4*)(gp + 4)  = c1;
        *(f32x4*)(gp + 8)  = c2;
        *(f32x4*)(gp + 12) = c3;
        *(f32x4*)(gp + 16) = k0;
        *(float2*)(out_bag + row * 2) = make_float2((float)ch, (float)co);
    }
}

extern "C" void kernel_launch(void* const* d_in, const int* in_sizes, int n_in,
                              void* d_out, int out_size, void* d_ws, size_t ws_size,
                              hipStream_t stream) {
    const int* gchar = (const int*)d_in[0];
    const int* gcol  = (const int*)d_in[1];
    const float* ctab = (const float*)d_in[2];
    const float* ktab = (const float*)d_in[3];
    const float* Wih  = (const float*)d_in[4];
    const float* Whh  = (const float*)d_in[5];
    const float* bih  = (const float*)d_in[6];
    const float* bhh  = (const float*)d_in[7];

    const int B = in_sizes[0] / HW;          // 4096
    float* out_h   = (float*)d_out;                    // B*32
    float* out_emb = out_h + (long)B * 32;             // B*64*20
    float* out_bag = out_emb + (long)B * 64 * 20;      // B*64*2

    unsigned short* ids_bt = (unsigned short*)d_ws;            // B*64 u16
    unsigned short* ids_tb = ids_bt + (long)B * 64;            // B*64 u16
    int*            lens_g = (int*)((char*)d_ws + (long)B * 64 * 4);  // B ints

    k1_histo<<<B / 4, 256, 0, stream>>>(gchar, gcol, ids_bt, ids_tb, lens_g);

    const int nrnn = B / 64;                 // 64 RNN blocks (first in grid)
    const int nemb = (B * 64) / 256;         // 1024 emb blocks
    k23_main<<<nrnn + nemb, 256, 0, stream>>>(
        ctab, ktab, Wih, Whh, bih, bhh, ids_bt, ids_tb, lens_g,
        out_h, out_emb, out_bag, nrnn);
}